// Round 1
// baseline (1258.611 us; speedup 1.0000x reference)
//
#include <hip/hip_runtime.h>
#include <hip/hip_bf16.h>
#include <float.h>
#include <math.h>

// ---------------------------------------------------------------------------
// UltraMemLayerV1 — round 1: all-f32 faithful pipeline (correctness first).
// Pipeline:
//   k_prep   : keys -> layernormed, tucker-rank-expanded B1/B2 (256 x 4096)
//   k_gemm   : hidden(4096x2048) @ wq(2048x512) -> qraw
//   k_ln_q   : per-(b,side) LN(256) -> q1n, q2n
//   k_gemm   : q1n @ B1 -> s_r (4096x4096: cols = (h,k,r))   [side 1]
//   k_topk1  : per (b,h): s = u-combine(rank pair); top-32 -> i1, g1
//   k_gemm   : q2n @ B2 -> s_r (reused)                       [side 2]
//   k_topk1  : -> i2, g2
//   k_stage2 : 32x32 tucker bilinear scores, top-32, softmax, shuffle lookup
//   k_agg    : weighted gather of value rows into agg (4096x1024)
//   k_gemm   : agg @ wv -> out (4096x2048)
// ---------------------------------------------------------------------------

__device__ __forceinline__ float wave_sum(float x) {
#pragma unroll
  for (int o = 32; o; o >>= 1) x += __shfl_xor(x, o, 64);
  return x;
}

// ---------------- keys prep: LN over d, fold knorm, layout B[d][col] --------
__global__ void k_prep(const float* __restrict__ keys, const float* __restrict__ knw,
                       float* __restrict__ B1, float* __restrict__ B2) {
  const int vid = blockIdx.x;        // 8192 = c(2) * h(2) * k(1024) * r(2)
  const int lane = threadIdx.x;      // 64
  const int r = vid & 1;
  const int k = (vid >> 1) & 1023;
  const int h = (vid >> 11) & 1;
  const int c = vid >> 12;
  // keys shape (h, c, k, d, r): elem (h,c,k,d,r) at (((h*2+c)*1024+k)*256+d)*2+r
  const float* base = keys + ((size_t)((h * 2 + c) * 1024 + k) * 256) * 2 + r;
  float x[4];
  float s = 0.f, sq = 0.f;
#pragma unroll
  for (int i = 0; i < 4; ++i) {
    x[i] = base[(size_t)(lane + (i << 6)) * 2];
    s += x[i];
    sq += x[i] * x[i];
  }
  s = wave_sum(s);
  sq = wave_sum(sq);
  const float mean = s * (1.f / 256.f);
  const float var = sq * (1.f / 256.f) - mean * mean;
  const float rs = 1.f / sqrtf(var + 1e-5f);
  float* Bc = (c == 0) ? B1 : B2;
  const int col = (h * 1024 + k) * 2 + r;
#pragma unroll
  for (int i = 0; i < 4; ++i) {
    const int d = lane + (i << 6);
    Bc[(size_t)d * 4096 + col] = (x[i] - mean) * rs * knw[d];
  }
}

// ---------------- q layernorm ----------------------------------------------
__global__ void k_ln_q(const float* __restrict__ qraw, const float* __restrict__ qnw,
                       float* __restrict__ q1n, float* __restrict__ q2n) {
  const int bid = blockIdx.x;  // 8192 = b*2 + c
  const int lane = threadIdx.x;
  const int b = bid >> 1, c = bid & 1;
  const float4 x = *(const float4*)&qraw[(size_t)b * 512 + c * 256 + lane * 4];
  float s = x.x + x.y + x.z + x.w;
  float sq = x.x * x.x + x.y * x.y + x.z * x.z + x.w * x.w;
  s = wave_sum(s);
  sq = wave_sum(sq);
  const float mean = s * (1.f / 256.f);
  const float var = sq * (1.f / 256.f) - mean * mean;
  const float rs = 1.f / sqrtf(var + 1e-5f);
  const float4 w4 = *(const float4*)&qnw[lane * 4];
  float4 o;
  o.x = (x.x - mean) * rs * w4.x;
  o.y = (x.y - mean) * rs * w4.y;
  o.z = (x.z - mean) * rs * w4.z;
  o.w = (x.w - mean) * rs * w4.w;
  float* dst = (c == 0) ? q1n : q2n;
  *(float4*)&dst[(size_t)b * 256 + lane * 4] = o;
}

// ---------------- generic f32 tiled GEMM: C = A(MxK) @ B(KxN) ---------------
template <int BM, int BN, int TM, int TN>
__global__ __launch_bounds__(256) void k_gemm(const float* __restrict__ A,
                                              const float* __restrict__ B,
                                              float* __restrict__ C,
                                              int M, int N, int K) {
  constexpr int BK = 32;
  __shared__ float As[BK][BM];  // transposed A tile: [k][m]
  __shared__ float Bs[BK][BN];  // [k][n]
  const int tid = threadIdx.x;
  const int tx = tid & 15, ty = tid >> 4;  // 16 x 16 thread grid
  const int bm = blockIdx.x * BM, bn = blockIdx.y * BN;
  float acc[TM][TN] = {};
  for (int k0 = 0; k0 < K; k0 += BK) {
    // stage A: BM x 32 floats, float4 global loads, scalar transpose-scatter
#pragma unroll
    for (int q = tid; q < BM * 8; q += 256) {
      const int r = q >> 3, kq = q & 7;
      const float4 v = *(const float4*)&A[(size_t)(bm + r) * K + k0 + kq * 4];
      As[kq * 4 + 0][r] = v.x;
      As[kq * 4 + 1][r] = v.y;
      As[kq * 4 + 2][r] = v.z;
      As[kq * 4 + 3][r] = v.w;
    }
    // stage B: 32 x BN floats, float4 direct
#pragma unroll
    for (int q = tid; q < BN * 8; q += 256) {
      const int kk = q / (BN / 4), nq = q % (BN / 4);
      const float4 v = *(const float4*)&B[(size_t)(k0 + kk) * N + bn + nq * 4];
      *(float4*)&Bs[kk][nq * 4] = v;
    }
    __syncthreads();
#pragma unroll
    for (int kk = 0; kk < BK; ++kk) {
      float a[TM], b[TN];
#pragma unroll
      for (int u = 0; u < TM; u += 4)
        *(float4*)&a[u] = *(const float4*)&As[kk][ty * TM + u];
#pragma unroll
      for (int u = 0; u < TN; u += 4)
        *(float4*)&b[u] = *(const float4*)&Bs[kk][tx * TN + u];
#pragma unroll
      for (int i = 0; i < TM; ++i)
#pragma unroll
        for (int j = 0; j < TN; ++j) acc[i][j] += a[i] * b[j];
    }
    __syncthreads();
  }
#pragma unroll
  for (int i = 0; i < TM; ++i)
#pragma unroll
    for (int j = 0; j < TN; j += 4) {
      float4 v = {acc[i][j], acc[i][j + 1], acc[i][j + 2], acc[i][j + 3]};
      *(float4*)&C[(size_t)(bm + ty * TM + i) * N + bn + tx * TN + j] = v;
    }
}

// ---------------- stage-1 top-32 over 1024 keys (one wave per (b,h)) --------
__global__ void k_topk1(const float* __restrict__ s_r, const float* __restrict__ uvec,
                        int* __restrict__ i_out, float* __restrict__ g_out) {
  const int bh = blockIdx.x;  // b*2 + h
  const int lane = threadIdx.x;
  const int h = bh & 1;
  const float u0 = uvec[h * 2 + 0], u1 = uvec[h * 2 + 1];
  const float* row = s_r + (size_t)bh * 2048;  // (b*4096 + h*2048)
  float sv[16];
#pragma unroll
  for (int i = 0; i < 16; ++i) {
    const float2 p = *(const float2*)&row[(lane + (i << 6)) * 2];
    sv[i] = p.x * u0 + p.y * u1;
  }
  int win_k = 0;
  for (int it = 0; it < 32; ++it) {
    float bv = -FLT_MAX;
    int bk = 0x7FFFFFFF;
#pragma unroll
    for (int i = 0; i < 16; ++i) {
      const int kk = lane + (i << 6);
      if (sv[i] > bv || (sv[i] == bv && kk < bk)) { bv = sv[i]; bk = kk; }
    }
#pragma unroll
    for (int o = 32; o; o >>= 1) {
      const float ov = __shfl_xor(bv, o, 64);
      const int ok = __shfl_xor(bk, o, 64);
      if (ov > bv || (ov == bv && ok < bk)) { bv = ov; bk = ok; }
    }
    if ((bk & 63) == lane) sv[bk >> 6] = -FLT_MAX;  // remove winner
    if (lane == it) win_k = bk;                     // lanes 0..31 hold winners
  }
  if (lane < 32) {
    i_out[bh * 32 + lane] = win_k;
    const float2 p = *(const float2*)&row[win_k * 2];
    g_out[(bh * 32 + lane) * 2 + 0] = p.x;
    g_out[(bh * 32 + lane) * 2 + 1] = p.y;
  }
}

// ---------------- stage-2: 32x32 bilinear scores, top-32, softmax -----------
__global__ void k_stage2(const float* __restrict__ g1, const float* __restrict__ g2,
                         const int* __restrict__ i1, const int* __restrict__ i2,
                         const float* __restrict__ tucker_core,
                         const int* __restrict__ shuffle_index,
                         float* __restrict__ w_out, int* __restrict__ sh_out) {
  __shared__ float sg1x[32], sg1y[32], sg2x[32], sg2y[32];
  __shared__ int si1[32], si2[32];
  const int bh = blockIdx.x;
  const int h = bh & 1;
  const int lane = threadIdx.x;
  if (lane < 32) {
    const float2 p1 = *(const float2*)&g1[(bh * 32 + lane) * 2];
    const float2 p2 = *(const float2*)&g2[(bh * 32 + lane) * 2];
    sg1x[lane] = p1.x;
    sg1y[lane] = p1.y;
    sg2x[lane] = p2.x;
    sg2y[lane] = p2.y;
    si1[lane] = i1[bh * 32 + lane];
    si2[lane] = i2[bh * 32 + lane];
  }
  __syncthreads();
  // C[h][r][s] = sum_m tucker_core[m,h,r,s]; flat m*8 + h*4 + r*2 + s
  const float c00 = tucker_core[h * 4 + 0] + tucker_core[8 + h * 4 + 0];
  const float c01 = tucker_core[h * 4 + 1] + tucker_core[8 + h * 4 + 1];
  const float c10 = tucker_core[h * 4 + 2] + tucker_core[8 + h * 4 + 2];
  const float c11 = tucker_core[h * 4 + 3] + tucker_core[8 + h * 4 + 3];
  float sv[16];
#pragma unroll
  for (int i = 0; i < 16; ++i) {
    const int p = lane + (i << 6);  // p = k*32 + l (flattened jax order)
    const int k = p >> 5, l = p & 31;
    const float a0 = sg1x[k] * c00 + sg1y[k] * c10;
    const float a1 = sg1x[k] * c01 + sg1y[k] * c11;
    sv[i] = a0 * sg2x[l] + a1 * sg2y[l];
  }
  float m0 = 0.f, Z = 0.f, win_e = 0.f;
  int win_p = 0;
  for (int it = 0; it < 32; ++it) {
    float bv = -FLT_MAX;
    int bp = 0x7FFFFFFF;
#pragma unroll
    for (int i = 0; i < 16; ++i) {
      const int p = lane + (i << 6);
      if (sv[i] > bv || (sv[i] == bv && p < bp)) { bv = sv[i]; bp = p; }
    }
#pragma unroll
    for (int o = 32; o; o >>= 1) {
      const float ov = __shfl_xor(bv, o, 64);
      const int op = __shfl_xor(bp, o, 64);
      if (ov > bv || (ov == bv && op < bp)) { bv = ov; bp = op; }
    }
    if (it == 0) m0 = bv;  // iteration-0 winner is the max
    const float e = expf(bv - m0);
    Z += e;
    if ((bp & 63) == lane) sv[bp >> 6] = -FLT_MAX;
    if (lane == it) { win_e = e; win_p = bp; }
  }
  if (lane < 32) {
    const int k = win_p >> 5, l = win_p & 31;
    const int ai = si1[k] * 1024 + si2[l];
    const int sh = shuffle_index[ai];  // = (eidx<<18) | vidx  (value_num = 2^18)
    w_out[bh * 32 + lane] = win_e / Z;
    sh_out[bh * 32 + lane] = sh;
  }
}

// ---------------- weighted value gather/aggregate (deterministic) -----------
__global__ __launch_bounds__(256) void k_agg(const float* __restrict__ w_out,
                                             const int* __restrict__ sh_out,
                                             const float* __restrict__ values,
                                             float* __restrict__ aggws) {
  __shared__ float acc[4][1024];  // per-wave private copy: [wave][e*256 + v]
  const int b = blockIdx.x;
  const int tid = threadIdx.x;
  const int wave = tid >> 6, lane = tid & 63;
  for (int i = tid; i < 4096; i += 256) ((float*)acc)[i] = 0.f;
  __syncthreads();
  for (int j = wave; j < 64; j += 4) {  // 64 = head(2) * 32 selected
    const float wgt = w_out[b * 64 + j];
    const int sh = sh_out[b * 64 + j];
    const int vidx = sh & 0x3FFFF;
    const int e = sh >> 18;
    const float4 v = *(const float4*)&values[(size_t)vidx * 256 + lane * 4];
    float* dst = &acc[wave][e * 256 + lane * 4];
    dst[0] += wgt * v.x;
    dst[1] += wgt * v.y;
    dst[2] += wgt * v.z;
    dst[3] += wgt * v.w;
  }
  __syncthreads();
  for (int i = tid; i < 1024; i += 256)
    aggws[(size_t)b * 1024 + i] = acc[0][i] + acc[1][i] + acc[2][i] + acc[3][i];
}

// ---------------------------------------------------------------------------
extern "C" void kernel_launch(void* const* d_in, const int* in_sizes, int n_in,
                              void* d_out, int out_size, void* d_ws, size_t ws_size,
                              hipStream_t stream) {
  const float* hidden = (const float*)d_in[0];
  const float* wq     = (const float*)d_in[1];
  const float* qnw    = (const float*)d_in[2];
  const float* knw    = (const float*)d_in[3];
  const float* keys   = (const float*)d_in[4];
  const float* tcore  = (const float*)d_in[5];
  const float* tu     = (const float*)d_in[6];
  const float* tv     = (const float*)d_in[7];
  const float* values = (const float*)d_in[8];
  const float* wvm    = (const float*)d_in[9];
  const int*   shuf   = (const int*)d_in[10];
  float* out = (float*)d_out;

  char* ws = (char*)d_ws;
  size_t off = 0;
  auto alloc = [&](size_t bytes) -> void* {
    void* p = ws + off;
    off += (bytes + 255) & ~(size_t)255;
    return p;
  };
  float* B1   = (float*)alloc((size_t)256 * 4096 * 4);   //  4 MB
  float* B2   = (float*)alloc((size_t)256 * 4096 * 4);   //  4 MB
  float* qraw = (float*)alloc((size_t)4096 * 512 * 4);   //  8 MB
  float* q1n  = (float*)alloc((size_t)4096 * 256 * 4);   //  4 MB
  float* q2n  = (float*)alloc((size_t)4096 * 256 * 4);   //  4 MB
  int*   i1   = (int*)  alloc((size_t)8192 * 32 * 4);    //  1 MB
  int*   i2   = (int*)  alloc((size_t)8192 * 32 * 4);    //  1 MB
  float* g1   = (float*)alloc((size_t)8192 * 64 * 4);    //  2 MB
  float* g2   = (float*)alloc((size_t)8192 * 64 * 4);    //  2 MB
  float* wgt  = (float*)alloc((size_t)8192 * 32 * 4);    //  1 MB
  int*   sho  = (int*)  alloc((size_t)8192 * 32 * 4);    //  1 MB
  float* aggb = (float*)alloc((size_t)4096 * 1024 * 4);  // 16 MB
  float* s_r  = (float*)alloc((size_t)4096 * 4096 * 4);  // 64 MB (reused both sides)
  (void)ws_size; (void)in_sizes; (void)n_in; (void)out_size;

  // 1) keys -> B1/B2
  k_prep<<<8192, 64, 0, stream>>>(keys, knw, B1, B2);
  // 2) q projection
  k_gemm<64, 64, 4, 4><<<dim3(4096 / 64, 512 / 64), 256, 0, stream>>>(
      hidden, wq, qraw, 4096, 512, 2048);
  // 3) q layernorm
  k_ln_q<<<8192, 64, 0, stream>>>(qraw, qnw, q1n, q2n);
  // 4) side-1 scores + top-32
  k_gemm<128, 128, 8, 8><<<dim3(4096 / 128, 4096 / 128), 256, 0, stream>>>(
      q1n, B1, s_r, 4096, 4096, 256);
  k_topk1<<<8192, 64, 0, stream>>>(s_r, tu, i1, g1);
  // 5) side-2 scores + top-32 (s_r reused)
  k_gemm<128, 128, 8, 8><<<dim3(4096 / 128, 4096 / 128), 256, 0, stream>>>(
      q2n, B2, s_r, 4096, 4096, 256);
  k_topk1<<<8192, 64, 0, stream>>>(s_r, tv, i2, g2);
  // 6) stage-2 bilinear scores, top-32, softmax, shuffle
  k_stage2<<<8192, 64, 0, stream>>>(g1, g2, i1, i2, tcore, shuf, wgt, sho);
  // 7) weighted value gather
  k_agg<<<4096, 256, 0, stream>>>(wgt, sho, values, aggb);
  // 8) output projection
  k_gemm<128, 128, 8, 8><<<dim3(4096 / 128, 2048 / 128), 256, 0, stream>>>(
      aggb, wvm, out, 4096, 2048, 1024);
}